// Round 7
// baseline (194.918 us; speedup 1.0000x reference)
//
#include <hip/hip_runtime.h>
#include <hip/hip_bf16.h>
#include <math.h>

#define EDIM 256
#define HDIM 256
#define BDIM 64
#define TDIM 2048
#define NC   64
#define TC   32
#define CPB  4      // chunks per persistent block

typedef __attribute__((ext_vector_type(8)))  short  short8;
typedef __attribute__((ext_vector_type(4)))  float  floatx4;
typedef __attribute__((ext_vector_type(4)))  unsigned int uintx4;

__device__ __forceinline__ unsigned short f2bf(float f) {
    unsigned int u = __float_as_uint(f);
    u += 0x7FFFu + ((u >> 16) & 1u);      // RNE
    return (unsigned short)(u >> 16);
}
__device__ __forceinline__ unsigned int pk2(float a, float b) {
    return (unsigned int)f2bf(a) | ((unsigned int)f2bf(b) << 16);
}
__device__ __forceinline__ float sigm(float x) {
    return __builtin_amdgcn_rcpf(1.f + __expf(-x));
}
__device__ __forceinline__ float tanh_fast(float x) {
    return fmaf(-2.f, __builtin_amdgcn_rcpf(1.f + __expf(2.f * x)), 1.f);
}

// Pack kernel:
//  bx < 256 : Wp fragment-pack (R0 layout).
//  bx >= 256 (mode==1): emb -> bf16 table.
__global__ __launch_bounds__(256) void qrnn_pack(
    const float* __restrict__ Wq, const float* __restrict__ emb,
    unsigned short* __restrict__ Wp, unsigned short* __restrict__ ebf,
    int mode)
{
    const int bx = blockIdx.x;
    if (bx < 256) {
        const int nt = (bx >> 3) & 7;
        const int hg = bx >> 6;
        const int ks = bx & 7;
        const int t = threadIdx.x;
        const int lane = t >> 2, pj = t & 3;
        const int col = lane & 15, q = lane >> 4;
        const int h = hg * 64 + (nt & 3) * 16 + col;
        const int c = (nt < 4) ? h : (HDIM + h);
        const int k = ks * 32 + q * 8 + pj * 2;
        unsigned int v = pk2(Wq[k * (3 * HDIM) + c], Wq[(k + 1) * (3 * HDIM) + c]);
        *(unsigned int*)(Wp + (size_t)bx * 512 + lane * 8 + pj * 2) = v;
    } else if (mode == 1) {
        size_t i = ((size_t)(bx - 256) * 256 + threadIdx.x) * 8;
        floatx4 a = *(const floatx4*)(emb + i);
        floatx4 b = *(const floatx4*)(emb + i + 4);
        uintx4 o = {pk2(a.x, a.y), pk2(a.z, a.w), pk2(b.x, b.y), pk2(b.z, b.w)};
        *(uintx4*)(ebf + i) = o;
    }
}

// Main (R6 structure) + FUSED COMBINE.  512 blocks x 512 thr (8 waves),
// 2 blocks/CU.  Each wave: 1 batch x 64 h x 4 chunks.  A-prefetch deepened
// to 4-ahead (abuf[5]) to cover L3-gather latency.
// After the chunk loop each block bumps cnt[bg] (agent scope); the LAST of
// the 64 blocks sharing a bg (16 cg x 4 hg) acquires and runs combine for
// its 8 batches -- no grid barrier, no spin, no co-residency assumption.
template<int MODE>
__global__ __launch_bounds__(512, 2) void qrnn_mfma(
    const int* __restrict__ X, const float* __restrict__ emb,
    const unsigned short* __restrict__ ebf, const unsigned short* __restrict__ Wp,
    const float* __restrict__ bq, float* __restrict__ wsA, float* __restrict__ wsB,
    unsigned int* __restrict__ cnt,
    const float* __restrict__ c0, const float* __restrict__ Wq,
    const float* __restrict__ Wout, const float* __restrict__ bout,
    float* __restrict__ out)
{
    __shared__ __align__(16) short Bsh[32768];   // 64 KB: [nt*8+ks][64 lanes][8]

    const int tid = threadIdx.x;
    const int cg = blockIdx.x, bg = blockIdx.y, hg = blockIdx.z;
    const int lane = tid & 63, w = tid >> 6;     // w in [0,8)
    const int col = lane & 15, q = lane >> 4;

    // Stage B slice (64 KB, all ks) once: 64 rows / 8 waves = 8 each.
    const unsigned short* wpb = Wp + (size_t)hg * 32768;
#pragma unroll
    for (int i = 0; i < 8; ++i) {
        const int ch = w * 8 + i;           // wave-uniform
        __builtin_amdgcn_global_load_lds(
            (const __attribute__((address_space(1))) unsigned int*)(wpb + ch * 512 + lane * 8),
            (__attribute__((address_space(3))) unsigned int*)(Bsh + ch * 512),
            16, 0, 0);
    }

    const int b0 = bg * 8 + w;              // one batch per wave
    int xid[CPB][2];
#pragma unroll
    for (int c = 0; c < CPB; ++c)
#pragma unroll
        for (int mt = 0; mt < 2; ++mt)
            xid[c][mt] = X[b0 * TDIM + (cg * CPB + c) * TC + mt * 16 + col];

    const int hbase = hg * 64;
    float bz[4], bff[4];
#pragma unroll
    for (int nt = 0; nt < 4; ++nt) {
        bz[nt]  = bq[hbase + nt * 16 + col];
        bff[nt] = bq[HDIM + hbase + nt * 16 + col];
    }

    short8 abuf[5][2];                      // 5 slots, 4-ahead pipeline
    auto fetchA = [&](int c, int ks, int slot) {
#pragma unroll
        for (int mt = 0; mt < 2; ++mt) {
            if constexpr (MODE == 1) {
                abuf[slot][mt] = *(const short8*)(ebf + (size_t)xid[c][mt] * EDIM + q * 8 + ks * 32);
            } else {
                const float* ap = emb + (size_t)xid[c][mt] * EDIM + q * 8 + ks * 32;
                floatx4 f0 = *(const floatx4*)ap;
                floatx4 f1 = *(const floatx4*)(ap + 4);
                uintx4 p = {pk2(f0.x, f0.y), pk2(f0.z, f0.w),
                            pk2(f1.x, f1.y), pk2(f1.z, f1.w)};
                abuf[slot][mt] = *(short8*)&p;
            }
        }
    };

    floatx4 acc[2][8];
#pragma unroll
    for (int mt = 0; mt < 2; ++mt)
#pragma unroll
        for (int nt = 0; nt < 8; ++nt) acc[mt][nt] = (floatx4){0.f, 0.f, 0.f, 0.f};

    fetchA(0, 0, 0);
    fetchA(0, 1, 1);
    fetchA(0, 2, 2);
    fetchA(0, 3, 3);
    __syncthreads();   // waits staging vmem too

#pragma unroll
    for (int c = 0; c < CPB; ++c) {
#pragma unroll
        for (int ks = 0; ks < 8; ++ks) {
            const int s = c * 8 + ks;
            if (s + 4 < CPB * 8)
                fetchA((s + 4) >> 3, (s + 4) & 7, (s + 4) % 5);
            short8 bf[8];
#pragma unroll
            for (int nt = 0; nt < 8; ++nt)
                bf[nt] = *(const short8*)(Bsh + (nt * 8 + ks) * 512 + lane * 8);
            const int sl = s % 5;
#pragma unroll
            for (int nt = 0; nt < 8; ++nt)
#pragma unroll
                for (int mt = 0; mt < 2; ++mt)
                    acc[mt][nt] = __builtin_amdgcn_mfma_f32_16x16x32_bf16(abuf[sl][mt], bf[nt], acc[mt][nt], 0, 0, 0);
        }

        // Epilogue for chunk cc: t = q*4 + j (+16*mt), h-col = nt*16+col.
        const int cc = cg * CPB + c;
        float Af[4], Bf[4];
#pragma unroll
        for (int nt = 0; nt < 4; ++nt) {
            float Aseg[2], Bseg[2];
#pragma unroll
            for (int mt = 0; mt < 2; ++mt) {
                float Ac = 1.f, Bc = 0.f;
#pragma unroll
                for (int j = 0; j < 4; ++j) {
                    float z = tanh_fast(acc[mt][nt][j] + bz[nt]);
                    float f = sigm(acc[mt][nt + 4][j] + bff[nt]);
                    Ac = f * Ac;
                    Bc = fmaf(f, Bc, (1.f - f) * z);
                }
                Aseg[mt] = Ac; Bseg[mt] = Bc;
            }
#pragma unroll
            for (int st = 0; st < 2; ++st) {
                const int msk = 16 << st;
                const bool self_earlier = ((q >> st) & 1) == 0;
#pragma unroll
                for (int mt = 0; mt < 2; ++mt) {
                    float Ap = __shfl_xor(Aseg[mt], msk, 64);
                    float Bp = __shfl_xor(Bseg[mt], msk, 64);
                    Bseg[mt] = self_earlier ? fmaf(Ap, Bseg[mt], Bp)
                                            : fmaf(Aseg[mt], Bp, Bseg[mt]);
                    Aseg[mt] = Aseg[mt] * Ap;
                }
            }
            Af[nt] = Aseg[0] * Aseg[1];                 // full 32-t chunk, batch b0
            Bf[nt] = fmaf(Aseg[1], Bseg[0], Bseg[1]);
        }

        float As = (q == 0) ? Af[0] : (q == 1) ? Af[1] : (q == 2) ? Af[2] : Af[3];
        float Bs = (q == 0) ? Bf[0] : (q == 1) ? Bf[1] : (q == 2) ? Bf[2] : Bf[3];

        const size_t r0 = ((size_t)cc * BDIM + b0) * HDIM + hbase + lane;
        wsA[r0] = As;
        wsB[r0] = Bs;

#pragma unroll
        for (int mt = 0; mt < 2; ++mt)
#pragma unroll
            for (int nt = 0; nt < 8; ++nt) acc[mt][nt] = (floatx4){0.f, 0.f, 0.f, 0.f};
    }

    // ---- Fused combine: last block of this bg-group does it. ----
    __syncthreads();                        // drains wsA/wsB stores (vmcnt 0)
    volatile int* flag = (volatile int*)Bsh;   // Bsh no longer needed
    if (tid == 0) {
        __builtin_amdgcn_fence(__ATOMIC_RELEASE, "agent");
        unsigned int old = __hip_atomic_fetch_add(&cnt[bg], 1u,
                               __ATOMIC_ACQ_REL, __HIP_MEMORY_SCOPE_AGENT);
        *flag = (old == 63u) ? 1 : 0;       // 64 blocks per bg (16 cg x 4 hg)
    }
    __syncthreads();
    if (*flag == 0) return;
    __builtin_amdgcn_fence(__ATOMIC_ACQUIRE, "agent");

    // This block combines batches bg*8 .. bg*8+7 with 512 threads.
    float* shf = (float*)Bsh;               // [0,512): xs (2 batches), [512,1024): red
    const int bi = tid >> 8;                // 0..1
    const int h  = tid & 255;
#pragma unroll 1
    for (int rep = 0; rep < 4; ++rep) {
        const int b = bg * 8 + rep * 2 + bi;

        float cacc = c0[b * HDIM + h];
        for (int c8 = 0; c8 < NC; c8 += 8) {
            float a[8], bb[8];
#pragma unroll
            for (int i = 0; i < 8; ++i) {
                size_t base = ((size_t)(c8 + i) * BDIM + b) * HDIM + h;
                a[i]  = wsA[base];
                bb[i] = wsB[base];
            }
#pragma unroll
            for (int i = 0; i < 8; ++i) cacc = fmaf(a[i], cacc, bb[i]);
        }

        int idx = X[b * TDIM + (TDIM - 1)];
        shf[bi * 256 + h] = emb[(size_t)idx * EDIM + h];
        __syncthreads();

        float dacc = 0.f;
#pragma unroll 16
        for (int e = 0; e < EDIM; ++e)
            dacc = fmaf(shf[bi * 256 + e], Wq[e * (3 * HDIM) + 2 * HDIM + h], dacc);

        float o  = 1.f / (1.f + expf(-(dacc + bq[2 * HDIM + h])));
        float hn = o * cacc;

        shf[512 + tid] = hn * Wout[h];
        __syncthreads();
        for (int s = HDIM / 2; s > 0; s >>= 1) {
            if (h < s) shf[512 + tid] += shf[512 + tid + s];
            __syncthreads();
        }
        if (h == 0) out[b] = shf[512 + bi * 256] + bout[0];
        __syncthreads();                    // LDS reuse across reps
    }
}

extern "C" void kernel_launch(void* const* d_in, const int* in_sizes, int n_in,
                              void* d_out, int out_size, void* d_ws, size_t ws_size,
                              hipStream_t stream) {
    const int*   X    = (const int*)d_in[0];
    const float* emb  = (const float*)d_in[1];
    const float* Wq   = (const float*)d_in[2];
    const float* bq   = (const float*)d_in[3];
    const float* c0   = (const float*)d_in[4];
    const float* Wout = (const float*)d_in[5];
    const float* bout = (const float*)d_in[6];
    float* out = (float*)d_out;

    // Workspace: [0,256) cnt (8 counters) | wsA | wsB | Wp | ebf.
    unsigned int* cnt = (unsigned int*)d_ws;
    float* wsA = (float*)((char*)d_ws + 256);         // [NC][B][H]
    float* wsB = wsA + (size_t)NC * BDIM * HDIM;      // [NC][B][H]
    unsigned short* Wp  = (unsigned short*)(wsB + (size_t)NC * BDIM * HDIM);  // 256 KB
    unsigned short* ebf = Wp + (size_t)256 * 512;     // 16.4 MB bf16 emb table

    const size_t wsAB = (size_t)2 * NC * BDIM * HDIM * 4;
    const size_t wpsz = (size_t)256 * 512 * 2;
    const size_t need1 = 256 + wsAB + wpsz + (size_t)32000 * EDIM * 2;   // ~25.0 MB
    const int mode = (ws_size >= need1) ? 1 : 0;

    (void)hipMemsetAsync(cnt, 0, 32, stream);   // re-arm per-bg counters each replay

    const int gather_blocks = (mode == 1) ? (32000 * EDIM / 8) / 256 : 0;  // 4000
    qrnn_pack<<<256 + gather_blocks, 256, 0, stream>>>(Wq, emb, Wp, ebf, mode);

    dim3 g(NC / CPB, BDIM / 8, HDIM / 64);   // 16 x 8 x 4 = 512 blocks of 512 thr (2/CU)
    if (mode == 1)
        qrnn_mfma<1><<<g, 512, 0, stream>>>(X, emb, ebf, Wp, bq, wsA, wsB,
                                            cnt, c0, Wq, Wout, bout, out);
    else
        qrnn_mfma<0><<<g, 512, 0, stream>>>(X, emb, ebf, Wp, bq, wsA, wsB,
                                            cnt, c0, Wq, Wout, bout, out);
}

// Round 8
// 143.625 us; speedup vs baseline: 1.3571x; 1.3571x over previous
//
#include <hip/hip_runtime.h>
#include <hip/hip_bf16.h>
#include <math.h>

#define EDIM 256
#define HDIM 256
#define BDIM 64
#define TDIM 2048
#define NC   64
#define TC   32
#define CPB  4      // chunks per persistent block

typedef __attribute__((ext_vector_type(8)))  short  short8;
typedef __attribute__((ext_vector_type(4)))  float  floatx4;
typedef __attribute__((ext_vector_type(4)))  unsigned int uintx4;

__device__ __forceinline__ unsigned short f2bf(float f) {
    unsigned int u = __float_as_uint(f);
    u += 0x7FFFu + ((u >> 16) & 1u);      // RNE
    return (unsigned short)(u >> 16);
}
__device__ __forceinline__ unsigned int pk2(float a, float b) {
    return (unsigned int)f2bf(a) | ((unsigned int)f2bf(b) << 16);
}
__device__ __forceinline__ float sigm(float x) {
    return __builtin_amdgcn_rcpf(1.f + __expf(-x));
}
__device__ __forceinline__ float tanh_fast(float x) {
    return fmaf(-2.f, __builtin_amdgcn_rcpf(1.f + __expf(2.f * x)), 1.f);
}

// Pack kernel:
//  bx < 256 : Wp fragment-pack (R0 layout).
//  bx >= 256 (mode==1): emb -> bf16 table.
__global__ __launch_bounds__(256) void qrnn_pack(
    const float* __restrict__ Wq, const float* __restrict__ emb,
    unsigned short* __restrict__ Wp, unsigned short* __restrict__ ebf,
    int mode)
{
    const int bx = blockIdx.x;
    if (bx < 256) {
        const int nt = (bx >> 3) & 7;
        const int hg = bx >> 6;
        const int ks = bx & 7;
        const int t = threadIdx.x;
        const int lane = t >> 2, pj = t & 3;
        const int col = lane & 15, q = lane >> 4;
        const int h = hg * 64 + (nt & 3) * 16 + col;
        const int c = (nt < 4) ? h : (HDIM + h);
        const int k = ks * 32 + q * 8 + pj * 2;
        unsigned int v = pk2(Wq[k * (3 * HDIM) + c], Wq[(k + 1) * (3 * HDIM) + c]);
        *(unsigned int*)(Wp + (size_t)bx * 512 + lane * 8 + pj * 2) = v;
    } else if (mode == 1) {
        size_t i = ((size_t)(bx - 256) * 256 + threadIdx.x) * 8;
        floatx4 a = *(const floatx4*)(emb + i);
        floatx4 b = *(const floatx4*)(emb + i + 4);
        uintx4 o = {pk2(a.x, a.y), pk2(a.z, a.w), pk2(b.x, b.y), pk2(b.z, b.w)};
        *(uintx4*)(ebf + i) = o;
    }
}

// Main: R6 structure (512 blocks x 512 thr, 8 waves, 1 batch/wave, 2 blk/CU)
// with the A-gather restructured from a 2-ahead 3-slot ring to a FLAT
// 16-deep burst: all 16 A-fragment loads for a chunk (abuf[8][2], statically
// indexed, single-buffered) issue back-to-back at chunk start.  In-order
// completion + compiler per-use vmcnt(N) means MFMA at step ks overlaps
// completion of loads ks+1..7 -> per-wave MLP 2 -> 16, one exposed L2/L3
// latency per chunk instead of ~8.  (R7's abuf[5] %5 ring spilled to
// scratch: VGPR 88->76, FETCH +4MB, 2x dur.  All indices here are
// compile-time after unroll; no ring phase.)
template<int MODE>
__global__ __launch_bounds__(512, 2) void qrnn_mfma(
    const int* __restrict__ X, const float* __restrict__ emb,
    const unsigned short* __restrict__ ebf, const unsigned short* __restrict__ Wp,
    const float* __restrict__ bq, float* __restrict__ wsA, float* __restrict__ wsB)
{
    __shared__ __align__(16) short Bsh[32768];   // 64 KB: [nt*8+ks][64 lanes][8]

    const int tid = threadIdx.x;
    const int cg = blockIdx.x, bg = blockIdx.y, hg = blockIdx.z;
    const int lane = tid & 63, w = tid >> 6;     // w in [0,8)
    const int col = lane & 15, q = lane >> 4;

    // Stage B slice (64 KB, all ks) once: 64 rows / 8 waves = 8 each.
    const unsigned short* wpb = Wp + (size_t)hg * 32768;
#pragma unroll
    for (int i = 0; i < 8; ++i) {
        const int ch = w * 8 + i;           // wave-uniform
        __builtin_amdgcn_global_load_lds(
            (const __attribute__((address_space(1))) unsigned int*)(wpb + ch * 512 + lane * 8),
            (__attribute__((address_space(3))) unsigned int*)(Bsh + ch * 512),
            16, 0, 0);
    }

    const int b0 = bg * 8 + w;              // one batch per wave
    int xid[CPB][2];
#pragma unroll
    for (int c = 0; c < CPB; ++c)
#pragma unroll
        for (int mt = 0; mt < 2; ++mt)
            xid[c][mt] = X[b0 * TDIM + (cg * CPB + c) * TC + mt * 16 + col];

    const int hbase = hg * 64;
    float bz[4], bff[4];
#pragma unroll
    for (int nt = 0; nt < 4; ++nt) {
        bz[nt]  = bq[hbase + nt * 16 + col];
        bff[nt] = bq[HDIM + hbase + nt * 16 + col];
    }

    floatx4 acc[2][8];
#pragma unroll
    for (int mt = 0; mt < 2; ++mt)
#pragma unroll
        for (int nt = 0; nt < 8; ++nt) acc[mt][nt] = (floatx4){0.f, 0.f, 0.f, 0.f};

    __syncthreads();   // Bsh staging complete (drains vmem)

#pragma unroll
    for (int c = 0; c < CPB; ++c) {
        // ---- Flat 16-deep A burst for this chunk (static indices). ----
        short8 abuf[8][2];
#pragma unroll
        for (int ks = 0; ks < 8; ++ks)
#pragma unroll
            for (int mt = 0; mt < 2; ++mt) {
                if constexpr (MODE == 1) {
                    abuf[ks][mt] = *(const short8*)(ebf + (size_t)xid[c][mt] * EDIM + q * 8 + ks * 32);
                } else {
                    const float* ap = emb + (size_t)xid[c][mt] * EDIM + q * 8 + ks * 32;
                    floatx4 f0 = *(const floatx4*)ap;
                    floatx4 f1 = *(const floatx4*)(ap + 4);
                    uintx4 p = {pk2(f0.x, f0.y), pk2(f0.z, f0.w),
                                pk2(f1.x, f1.y), pk2(f1.z, f1.w)};
                    abuf[ks][mt] = *(short8*)&p;
                }
            }

#pragma unroll
        for (int ks = 0; ks < 8; ++ks) {
            short8 bf[8];
#pragma unroll
            for (int nt = 0; nt < 8; ++nt)
                bf[nt] = *(const short8*)(Bsh + (nt * 8 + ks) * 512 + lane * 8);
#pragma unroll
            for (int nt = 0; nt < 8; ++nt)
#pragma unroll
                for (int mt = 0; mt < 2; ++mt)
                    acc[mt][nt] = __builtin_amdgcn_mfma_f32_16x16x32_bf16(abuf[ks][mt], bf[nt], acc[mt][nt], 0, 0, 0);
        }

        // Epilogue for chunk cc: t = q*4 + j (+16*mt), h-col = nt*16+col.
        const int cc = cg * CPB + c;
        float Af[4], Bf[4];
#pragma unroll
        for (int nt = 0; nt < 4; ++nt) {
            float Aseg[2], Bseg[2];
#pragma unroll
            for (int mt = 0; mt < 2; ++mt) {
                float Ac = 1.f, Bc = 0.f;
#pragma unroll
                for (int j = 0; j < 4; ++j) {
                    float z = tanh_fast(acc[mt][nt][j] + bz[nt]);
                    float f = sigm(acc[mt][nt + 4][j] + bff[nt]);
                    Ac = f * Ac;
                    Bc = fmaf(f, Bc, (1.f - f) * z);
                }
                Aseg[mt] = Ac; Bseg[mt] = Bc;
            }
#pragma unroll
            for (int st = 0; st < 2; ++st) {
                const int msk = 16 << st;
                const bool self_earlier = ((q >> st) & 1) == 0;
#pragma unroll
                for (int mt = 0; mt < 2; ++mt) {
                    float Ap = __shfl_xor(Aseg[mt], msk, 64);
                    float Bp = __shfl_xor(Bseg[mt], msk, 64);
                    Bseg[mt] = self_earlier ? fmaf(Ap, Bseg[mt], Bp)
                                            : fmaf(Aseg[mt], Bp, Bseg[mt]);
                    Aseg[mt] = Aseg[mt] * Ap;
                }
            }
            Af[nt] = Aseg[0] * Aseg[1];                 // full 32-t chunk, batch b0
            Bf[nt] = fmaf(Aseg[1], Bseg[0], Bseg[1]);
        }

        float As = (q == 0) ? Af[0] : (q == 1) ? Af[1] : (q == 2) ? Af[2] : Af[3];
        float Bs = (q == 0) ? Bf[0] : (q == 1) ? Bf[1] : (q == 2) ? Bf[2] : Bf[3];

        const size_t r0 = ((size_t)cc * BDIM + b0) * HDIM + hbase + lane;
        wsA[r0] = As;
        wsB[r0] = Bs;

#pragma unroll
        for (int mt = 0; mt < 2; ++mt)
#pragma unroll
            for (int nt = 0; nt < 8; ++nt) acc[mt][nt] = (floatx4){0.f, 0.f, 0.f, 0.f};
    }
}

// Combine chunk (A,B) pairs + o-gate at t=T-1 + output dot.
__global__ __launch_bounds__(256) void qrnn_combine(
    const float* __restrict__ wsA, const float* __restrict__ wsB,
    const float* __restrict__ c0, const int* __restrict__ X,
    const float* __restrict__ emb, const float* __restrict__ Wq,
    const float* __restrict__ bq, const float* __restrict__ Wout,
    const float* __restrict__ bout, float* __restrict__ out)
{
    const int b = blockIdx.x;
    const int h = threadIdx.x;

    float c = c0[b * HDIM + h];
    for (int c8 = 0; c8 < NC; c8 += 8) {
        float a[8], bb[8];
#pragma unroll
        for (int i = 0; i < 8; ++i) {
            size_t base = ((size_t)(c8 + i) * BDIM + b) * HDIM + h;
            a[i]  = wsA[base];
            bb[i] = wsB[base];
        }
#pragma unroll
        for (int i = 0; i < 8; ++i) c = fmaf(a[i], c, bb[i]);
    }

    __shared__ float xs[EDIM];
    int idx = X[b * TDIM + (TDIM - 1)];
    xs[h] = emb[(size_t)idx * EDIM + h];
    __syncthreads();

    float acc = 0.f;
#pragma unroll 16
    for (int e = 0; e < EDIM; ++e)
        acc = fmaf(xs[e], Wq[e * (3 * HDIM) + 2 * HDIM + h], acc);

    float o  = 1.f / (1.f + expf(-(acc + bq[2 * HDIM + h])));
    float hn = o * c;

    __shared__ float red[HDIM];
    red[h] = hn * Wout[h];
    __syncthreads();
    for (int s = HDIM / 2; s > 0; s >>= 1) {
        if (h < s) red[h] += red[h + s];
        __syncthreads();
    }
    if (h == 0) out[b] = red[0] + bout[0];
}

extern "C" void kernel_launch(void* const* d_in, const int* in_sizes, int n_in,
                              void* d_out, int out_size, void* d_ws, size_t ws_size,
                              hipStream_t stream) {
    const int*   X    = (const int*)d_in[0];
    const float* emb  = (const float*)d_in[1];
    const float* Wq   = (const float*)d_in[2];
    const float* bq   = (const float*)d_in[3];
    const float* c0   = (const float*)d_in[4];
    const float* Wout = (const float*)d_in[5];
    const float* bout = (const float*)d_in[6];
    float* out = (float*)d_out;

    float* wsA = (float*)d_ws;                        // [NC][B][H]
    float* wsB = wsA + (size_t)NC * BDIM * HDIM;      // [NC][B][H]
    unsigned short* Wp  = (unsigned short*)(wsB + (size_t)NC * BDIM * HDIM);  // 256 KB
    unsigned short* ebf = Wp + (size_t)256 * 512;     // 16.4 MB bf16 emb table

    const size_t wsAB = (size_t)2 * NC * BDIM * HDIM * 4;
    const size_t wpsz = (size_t)256 * 512 * 2;
    const size_t need1 = wsAB + wpsz + (size_t)32000 * EDIM * 2;   // ~25.0 MB
    const int mode = (ws_size >= need1) ? 1 : 0;

    const int gather_blocks = (mode == 1) ? (32000 * EDIM / 8) / 256 : 0;  // 4000
    qrnn_pack<<<256 + gather_blocks, 256, 0, stream>>>(Wq, emb, Wp, ebf, mode);

    dim3 g(NC / CPB, BDIM / 8, HDIM / 64);   // 16 x 8 x 4 = 512 blocks of 512 thr (2/CU)
    if (mode == 1) qrnn_mfma<1><<<g, 512, 0, stream>>>(X, emb, ebf, Wp, bq, wsA, wsB);
    else           qrnn_mfma<0><<<g, 512, 0, stream>>>(X, emb, ebf, Wp, bq, wsA, wsB);

    qrnn_combine<<<BDIM, 256, 0, stream>>>(wsA, wsB, c0, X, emb, Wq, bq, Wout, bout, out);
}